// Round 2
// baseline (345.004 us; speedup 1.0000x reference)
//
#include <hip/hip_runtime.h>

// Problem constants
#define CV   34          // C*V channels
#define TTOT 2048        // T
#define NB   512         // batches
#define XB   69632       // x per-batch stride (2*2048*17)
#define XC   34816       // x per-co stride (2048*17)

// Workspace layout (floats)
#define GS_STRIDE 1192                   // per-batch: G (1156) + s0 (34) + pad
#define RB_OFF    (512 * 1192)           // region B offset
// region B per batch: 1024 ushort (hi/lo bf16 planes, 16x32) = 512 f,
// then cy[16], wy32[16], wy33[16] f32 -> 560 f, padded to 576
#define RB_STRIDE 576

typedef __attribute__((ext_vector_type(8))) short v8s;   // 8 x bf16 (MFMA A/B frag)
typedef __attribute__((ext_vector_type(4))) float v4f;   // 4 x f32 (MFMA C/D frag)

__device__ __forceinline__ unsigned short f2bf(float f) {
    unsigned int u = __float_as_uint(f);
    u = u + 0x7FFFu + ((u >> 16) & 1u);   // round-to-nearest-even
    return (unsigned short)(u >> 16);
}
__device__ __forceinline__ float bf2f(unsigned short s) {
    return __uint_as_float(((unsigned int)s) << 16);
}

__device__ __forceinline__ unsigned int cvtpk_bf16(float a, float b) {
    unsigned int r;   // r.lo16 = bf16(a), r.hi16 = bf16(b), RNE
    asm("v_cvt_pk_bf16_f32 %0, %1, %2" : "=v"(r) : "v"(a), "v"(b));
    return r;
}

// split 8 f32 -> packed hi/lo bf16 MFMA fragments (RNE; residual exact in f32)
__device__ __forceinline__ void split8(const float (&f)[8], v8s* hi, v8s* lo) {
    union { unsigned int u[4]; v8s s; } H, L;
#pragma unroll
    for (int p = 0; p < 4; ++p) {
        float a = f[2 * p], b = f[2 * p + 1];
        unsigned int h = cvtpk_bf16(a, b);
        float ra = a - __uint_as_float(h << 16);
        float rb = b - __uint_as_float(h & 0xFFFF0000u);
        L.u[p] = cvtpk_bf16(ra, rb);
        H.u[p] = h;
    }
    *hi = H.s;
    *lo = L.s;
}

// async-stage one 128-t chunk (2 co x 2176 floats, verbatim global order) to LDS.
// 17 x global_load_lds(16B); wave w issues instrs {w, w+4, ...}.
__device__ __forceinline__ void stage_chunk(const float* __restrict__ xb, int t0,
                                            float* rawbuf, int w, int lane) {
#pragma unroll
    for (int i = 0; i < 5; ++i) {
        int idx = i * 4 + w;
        if (idx < 17) {
            int fl = idx * 256 + lane * 4;
            int co = (fl >= 2176) ? 1 : 0;
            const float* g = xb + t0 * 17 + fl + co * 32640;   // 32640 = XC - 2176
            __builtin_amdgcn_global_load_lds(
                (const __attribute__((address_space(1))) void*)g,
                (__attribute__((address_space(3))) void*)(rawbuf + idx * 256),
                16, 0, 0);
        }
    }
}

// ---------------------------------------------------------------------------
// K1: per-(batch, t-segment) partial Gram G += Hseg Hseg^T (34x34) and s0.
// Async f32 staging (double-buffered) + in-register hi/lo split at frag build.
// ---------------------------------------------------------------------------
struct SmemGramB {
    float Gpart[4][34][36];
    float spart[4][36];
};

__global__ __launch_bounds__(256, 4) void k_gram(const float* __restrict__ x,
                                                 float* __restrict__ ws) {
    __shared__ __align__(16) union {
        float raw[2][4352];      // 2 x (2 co x 2176 f32)  = 34,816 B
        SmemGramB b;             // epilogue reduction area = 20,160 B
    } sm;

    const int b    = blockIdx.x >> 2;
    const int seg  = blockIdx.x & 3;          // 4 segments of 512 t
    const int tid  = threadIdx.x;
    const int l    = tid & 63;
    const int w    = tid >> 6;                // wave id 0..3 -> k-slice in chunk
    const int row16 = l & 15;
    const int quad  = l >> 4;
    const float* xb = x + (size_t)b * XB;
    const int t0 = seg * 512;

    // per-lane dword offsets for channel c = r*16+row16 (clamped: rows 34..47
    // duplicate row 33; their MFMA outputs land in discarded C rows/cols)
    int offc[3];
#pragma unroll
    for (int r = 0; r < 3; ++r) {
        int c = r * 16 + row16;
        if (c > 33) c = 33;
        offc[r] = (c >= 17) ? (2159 + c) : c;   // = co*2176 + v
    }
    const int koff = w * 32 + quad * 8;        // t offset within 128-t chunk

    v4f accG[3][3];
    v4f accS[3];
    v4f vz = {0.f, 0.f, 0.f, 0.f};
#pragma unroll
    for (int r = 0; r < 3; ++r) {
        accS[r] = vz;
#pragma unroll
        for (int c = 0; c < 3; ++c) accG[r][c] = vz;
    }
    v8s ones;
#pragma unroll
    for (int i = 0; i < 8; ++i) ones[i] = (short)0x3F80;   // bf16 1.0

    stage_chunk(xb, t0, sm.raw[0], w, l);
    __syncthreads();                           // drains vmcnt(0): chunk 0 ready

    for (int ch = 0; ch < 4; ++ch) {           // 4 chunks of 128 t
        const int cur = ch & 1;
        if (ch < 3) stage_chunk(xb, t0 + (ch + 1) * 128, sm.raw[cur ^ 1], w, l);

        const float* rb = sm.raw[cur] + koff * 17;
        v8s fh[3], fl4[3];
#pragma unroll
        for (int r = 0; r < 3; ++r) {
            const float* p = rb + offc[r];
            float f[8];
#pragma unroll
            for (int e = 0; e < 8; ++e) f[e] = p[e * 17];   // 8 x ds_read_b32, imm offs
            split8(f, &fh[r], &fl4[r]);
        }
#pragma unroll
        for (int r = 0; r < 3; ++r) {
#pragma unroll
            for (int c = 0; c < 3; ++c) {
                accG[r][c] = __builtin_amdgcn_mfma_f32_16x16x32_bf16(fh[r],  fh[c],  accG[r][c], 0, 0, 0);
                accG[r][c] = __builtin_amdgcn_mfma_f32_16x16x32_bf16(fh[r],  fl4[c], accG[r][c], 0, 0, 0);
                accG[r][c] = __builtin_amdgcn_mfma_f32_16x16x32_bf16(fl4[r], fh[c],  accG[r][c], 0, 0, 0);
            }
            accS[r] = __builtin_amdgcn_mfma_f32_16x16x32_bf16(fh[r],  ones, accS[r], 0, 0, 0);
            accS[r] = __builtin_amdgcn_mfma_f32_16x16x32_bf16(fl4[r], ones, accS[r], 0, 0, 0);
        }
        __syncthreads();   // drains next-chunk stage; protects buffer reuse
    }

    // epilogue: union switched to sm.b (all raw reads complete + barrier passed)
#pragma unroll
    for (int r = 0; r < 3; ++r) {
#pragma unroll
        for (int c = 0; c < 3; ++c) {
#pragma unroll
            for (int i = 0; i < 4; ++i) {
                int m = r * 16 + quad * 4 + i;
                int n = c * 16 + row16;
                if (m < 34 && n < 34) sm.b.Gpart[w][m][n] = accG[r][c][i];
            }
        }
        if (row16 == 0) {
#pragma unroll
            for (int i = 0; i < 4; ++i) {
                int m = r * 16 + quad * 4 + i;
                if (m < 34) sm.b.spart[w][m] = accS[r][i];
            }
        }
    }
    __syncthreads();
    float* gout = ws + (size_t)b * GS_STRIDE;
    for (int idx = tid; idx < 1156; idx += 256) {
        int m = idx / 34, n = idx - m * 34;
        atomicAdd(&gout[idx], sm.b.Gpart[0][m][n] + sm.b.Gpart[1][m][n] +
                              sm.b.Gpart[2][m][n] + sm.b.Gpart[3][m][n]);
    }
    if (tid < 34)
        atomicAdd(&gout[1156 + tid], sm.b.spart[0][tid] + sm.b.spart[1][tid] +
                                     sm.b.spart[2][tid] + sm.b.spart[3][tid]);
}

// ---------------------------------------------------------------------------
// K2: per-batch affine chain, WAVE-SYNCHRONOUS (64 threads = 1 wave per batch,
// s_barrier is a no-op for single-wave workgroups). Augmented-matrix algebra:
// state At (A^T) carries the offset vector in row 34; G0b is the augmented
// Gram [[G, s0],[s0^T, T]] so scores = Aq^·G^·Ak^T exactly (no rank-1 fixups).
// ---------------------------------------------------------------------------

// D[i][j] = sum_{e<36} L[i][e]*R[j][e]. Lane tile: 9 rows (lr*9..+8) x cols
// {lc, lc+16, lc+32(if lc<3)}. L-reads broadcast per 16-lane group; R-reads
// 2-way bank-aliased (free). Col 35 never written (stays 0 from init).
__device__ __forceinline__ void wave_mm(const float (*__restrict__ L)[36],
                                        const float (*__restrict__ R)[36],
                                        float (*__restrict__ D)[36], int l) {
    const int lr = l >> 4, lc = l & 15;
    const int i0 = lr * 9;
    const bool has3 = (lc < 3);
    const int j3 = has3 ? (lc + 32) : 0;   // clamped row for safe load
    float a0[9], a1[9], a2[9];
#pragma unroll
    for (int a = 0; a < 9; ++a) { a0[a] = 0.f; a1[a] = 0.f; a2[a] = 0.f; }
#pragma unroll
    for (int e0 = 0; e0 < 36; e0 += 4) {
        const float4 r0 = *(const float4*)&R[lc][e0];
        const float4 r1 = *(const float4*)&R[lc + 16][e0];
        const float4 r2 = *(const float4*)&R[j3][e0];
#pragma unroll
        for (int a = 0; a < 9; ++a) {
            const float4 lv = *(const float4*)&L[i0 + a][e0];
            a0[a] += lv.x * r0.x + lv.y * r0.y + lv.z * r0.z + lv.w * r0.w;
            a1[a] += lv.x * r1.x + lv.y * r1.y + lv.z * r1.z + lv.w * r1.w;
            a2[a] += lv.x * r2.x + lv.y * r2.y + lv.z * r2.z + lv.w * r2.w;
        }
    }
#pragma unroll
    for (int a = 0; a < 9; ++a) {
        D[i0 + a][lc]      = a0[a];
        D[i0 + a][lc + 16] = a1[a];
        if (has3) D[i0 + a][lc + 32] = a2[a];
    }
}

// Same, L from global W (nrows x 34, row-major, stride 34), contraction e<34.
// Rows >= nrows contribute zero. transpose=1 writes D[j][i].
__device__ __forceinline__ void wave_mmG(const float* __restrict__ Wg, int nrows,
                                         const float (*__restrict__ R)[36],
                                         float (*__restrict__ D)[36],
                                         int transpose, int l) {
    const int lr = l >> 4, lc = l & 15;
    const int i0 = lr * 9;
    const bool has3 = (lc < 3);
    const int j3 = has3 ? (lc + 32) : 0;
    float a0[9], a1[9], a2[9];
#pragma unroll
    for (int a = 0; a < 9; ++a) { a0[a] = 0.f; a1[a] = 0.f; a2[a] = 0.f; }
#pragma unroll
    for (int e0 = 0; e0 < 32; e0 += 4) {
        const float4 r0 = *(const float4*)&R[lc][e0];
        const float4 r1 = *(const float4*)&R[lc + 16][e0];
        const float4 r2 = *(const float4*)&R[j3][e0];
#pragma unroll
        for (int a = 0; a < 9; ++a) {
            const int i = i0 + a;
            float2 la = make_float2(0.f, 0.f), lb = make_float2(0.f, 0.f);
            if (i < nrows) {
                la = *(const float2*)(Wg + i * 34 + e0);
                lb = *(const float2*)(Wg + i * 34 + e0 + 2);
            }
            a0[a] += la.x * r0.x + la.y * r0.y + lb.x * r0.z + lb.y * r0.w;
            a1[a] += la.x * r1.x + la.y * r1.y + lb.x * r1.z + lb.y * r1.w;
            a2[a] += la.x * r2.x + la.y * r2.y + lb.x * r2.z + lb.y * r2.w;
        }
    }
    {   // tail e = 32, 33
        const float r00 = R[lc][32],      r01 = R[lc][33];
        const float r10 = R[lc + 16][32], r11 = R[lc + 16][33];
        const float r20 = R[j3][32],      r21 = R[j3][33];
#pragma unroll
        for (int a = 0; a < 9; ++a) {
            const int i = i0 + a;
            float2 la = make_float2(0.f, 0.f);
            if (i < nrows) la = *(const float2*)(Wg + i * 34 + 32);
            a0[a] += la.x * r00 + la.y * r01;
            a1[a] += la.x * r10 + la.y * r11;
            a2[a] += la.x * r20 + la.y * r21;
        }
    }
#pragma unroll
    for (int a = 0; a < 9; ++a) {
        const int i = i0 + a;
        if (transpose) {
            D[lc][i]      = a0[a];
            D[lc + 16][i] = a1[a];
            if (has3) D[lc + 32][i] = a2[a];
        } else {
            D[i][lc]      = a0[a];
            D[i][lc + 16] = a1[a];
            if (has3) D[i][lc + 32] = a2[a];
        }
    }
}

__global__ __launch_bounds__(64) void k_chain(
    const float* __restrict__ wq, const float* __restrict__ bq,
    const float* __restrict__ wk, const float* __restrict__ bk,
    const float* __restrict__ wv, const float* __restrict__ bv,
    const float* __restrict__ w1, const float* __restrict__ b1,
    const float* __restrict__ gamma, const float* __restrict__ beta,
    const float* __restrict__ mean, const float* __restrict__ var,
    float* __restrict__ ws) {
    __shared__ float SM[7][36][36];
    float (*G0b)[36] = SM[0];   // augmented Gram [[G,s0],[s0^T,2048]]
    float (*At )[36] = SM[1];   // A^T, row 34 = offset vector a
    float (*Aq )[36] = SM[2];   // col 34 = Wq*a + bq
    float (*Ak )[36] = SM[3];
    float (*AvT)[36] = SM[4];   // row 34 = Wv*a + bv
    float (*S1 )[36] = SM[5];
    float (*Sc )[36] = SM[6];

    const int l = threadIdx.x;
    const int b = blockIdx.x;
    const float* gsb = ws + (size_t)b * GS_STRIDE;

    // zero all LDS: pads must be 0; col 35 / unwritten pads stay 0 forever
    {
        const float4 z = make_float4(0.f, 0.f, 0.f, 0.f);
        float* base = &SM[0][0][0];
        for (int i = l * 4; i < 9072; i += 256) *(float4*)(base + i) = z;
    }
    __syncthreads();
    // load augmented G0 and layer-0 shortcut (A = I, a = 0):
    // Aq=wq0 (+bq in col 34), Ak=wk0, AvT=wv0^T (+bv in row 34)
    for (int idx = l; idx < 1156; idx += 64) {
        int m = idx / 34, n = idx - m * 34;
        G0b[m][n] = gsb[idx];
        Aq[m][n] = wq[idx];
        Ak[m][n] = wk[idx];
        AvT[n][m] = wv[idx];
    }
    if (l < 34) {
        float s = gsb[1156 + l];
        G0b[34][l] = s;
        G0b[l][34] = s;
        Aq[l][34]  = bq[l];
        Ak[l][34]  = bk[l];
        AvT[34][l] = bv[l];
    }
    if (l == 0) G0b[34][34] = 2048.0f;
    __syncthreads();

    for (int lyr = 0; lyr < 3; ++lyr) {
        if (lyr > 0) {
            const float* wql = wq + lyr * 1156;
            const float* wkl = wk + lyr * 1156;
            const float* wvl = wv + lyr * 1156;
            // stage1: Aq^ = Wq*A^, Ak^ = Wk*A^, AvT^ = (Wv*A^)^T
            wave_mmG(wql, 34, At, Aq, 0, l);
            wave_mmG(wkl, 34, At, Ak, 0, l);
            wave_mmG(wvl, 34, At, AvT, 1, l);
            __syncthreads();
            if (l < 34) {     // add biases to the offset slots
                Aq[l][34]  += bq[lyr * 34 + l];
                Ak[l][34]  += bk[lyr * 34 + l];
                AvT[34][l] += bv[lyr * 34 + l];
            }
            __syncthreads();
        }
        // stage2: S1 = Aq^ * G0^   (G0^ symmetric => R[j][e]=G0b[j][e])
        wave_mm(Aq, G0b, S1, l);
        __syncthreads();
        // stage3: Sc = S1 * Ak^T = exact augmented scores (rank-1 terms via e=34)
        wave_mm(S1, Ak, Sc, l);
        __syncthreads();
        // stage4: row softmax (rows/cols < 34)
        if (l < 34) {
            float f[36];
#pragma unroll
            for (int e0 = 0; e0 < 36; e0 += 4)
                *(float4*)&f[e0] = *(const float4*)&Sc[l][e0];
            const float scale = 0.022097086912079608f;   // 1/sqrt(2048)
            float mx = -1e30f;
#pragma unroll
            for (int d = 0; d < 34; ++d) { f[d] *= scale; mx = fmaxf(mx, f[d]); }
            float sum = 0.f;
#pragma unroll
            for (int d = 0; d < 34; ++d) { float e = __expf(f[d] - mx); f[d] = e; sum += e; }
            float rs = 1.0f / sum;
#pragma unroll
            for (int d = 0; d < 34; ++d) f[d] *= rs;
            f[34] = 0.f; f[35] = 0.f;   // keep pads zero
#pragma unroll
            for (int e0 = 0; e0 < 36; e0 += 4)
                *(float4*)&Sc[l][e0] = *(const float4*)&f[e0];
        }
        __syncthreads();
        // stage5: At' = AvT^ * attn^T; row 34 (= AvT offset row) auto-propagates a'
        wave_mm(AvT, Sc, At, l);
        __syncthreads();
    }

    // head: S1[o][j] = (w1 * A3^)[o][j]; col 34 = W1*a (cy_raw - b1)
    wave_mmG(w1, 16, At, S1, 0, l);
    __syncthreads();
    // emit compact Wy': bf16 hi/lo planes for c<32, f32 cols 32/33, cy
    float* wb = ws + RB_OFF + (size_t)b * RB_STRIDE;
    if (l < 16) {
        float iv = gamma[l] * rsqrtf(var[l] + 1e-5f);
        float cyraw = S1[l][34] + b1[l];
        wb[512 + l] = (cyraw - mean[l]) * iv + beta[l];   // cy'
        wb[528 + l] = S1[l][32] * iv;                     // wy32
        wb[544 + l] = S1[l][33] * iv;                     // wy33
    }
    unsigned short* wp = (unsigned short*)wb;
    for (int i = l; i < 512; i += 64) {
        int o = i >> 5, c = i & 31;
        float iv = gamma[o] * rsqrtf(var[o] + 1e-5f);
        float vv = S1[o][c] * iv;
        unsigned short hb = f2bf(vv);
        wp[i] = hb;
        wp[512 + i] = f2bf(vv - bf2f(hb));
    }
}

// ---------------------------------------------------------------------------
// K3: out = w2 * leaky(Wy' h0 + cy') + b2. Async f32 staging + in-register
// split at B-frag build; channels 32/33 via exact f32 scalar FMA (MFMA halved).
// ---------------------------------------------------------------------------
__global__ __launch_bounds__(256, 4) void k_out(const float* __restrict__ x,
                                                const float* __restrict__ w2,
                                                const float* __restrict__ b2,
                                                const float* __restrict__ ws,
                                                float* __restrict__ out) {
    __shared__ __align__(16) float raw[2][4352];

    const int tid  = threadIdx.x;
    const int b    = blockIdx.x >> 3;
    const int seg  = (blockIdx.x & 7) * 256;
    const int l    = tid & 63;
    const int w    = tid >> 6;
    const int quad = l >> 4;
    const int col  = l & 15;

    const float* wb = ws + RB_OFF + (size_t)b * RB_STRIDE;
    const unsigned short* wp = (const unsigned short*)wb;
    v8s aH = *(const v8s*)&wp[col * 32 + quad * 8];
    v8s aL = *(const v8s*)&wp[512 + col * 32 + quad * 8];
    float cyr[4], w2r[3][4], wy32r[4], wy33r[4];
#pragma unroll
    for (int i = 0; i < 4; ++i) {
        int o = quad * 4 + i;
        cyr[i]   = wb[512 + o];
        wy32r[i] = wb[528 + o];
        wy33r[i] = wb[544 + o];
#pragma unroll
        for (int p = 0; p < 3; ++p) w2r[p][i] = w2[p * 16 + o];
    }
    float b2r[3] = {b2[0], b2[1], b2[2]};
    const float* xb = x + (size_t)b * XB;

    // per-lane dword offsets for channels c = quad*8+e (all real, c < 32)
    int offq[8];
#pragma unroll
    for (int e = 0; e < 8; ++e) {
        int c = quad * 8 + e;
        offq[e] = (c >= 17) ? (2159 + c) : c;   // = co*2176 + v
    }

    stage_chunk(xb, seg, raw[0], w, l);
    __syncthreads();

    for (int ch = 0; ch < 2; ++ch) {
        if (ch == 0) stage_chunk(xb, seg + 128, raw[1], w, l);
        for (int tt = w; tt < 8; tt += 4) {
            const int tl = tt * 16 + col;
            const float* rbt = raw[ch] + tl * 17;
            float f[8];
#pragma unroll
            for (int e = 0; e < 8; ++e) f[e] = rbt[offq[e]];
            v8s bH, bL;
            split8(f, &bH, &bL);
            v4f acc = {0.f, 0.f, 0.f, 0.f};
            acc = __builtin_amdgcn_mfma_f32_16x16x32_bf16(aH, bH, acc, 0, 0, 0);
            acc = __builtin_amdgcn_mfma_f32_16x16x32_bf16(aH, bL, acc, 0, 0, 0);
            acc = __builtin_amdgcn_mfma_f32_16x16x32_bf16(aL, bH, acc, 0, 0, 0);
            float h32 = rbt[2191];   // c=32 (co1, v15) — LDS broadcast across quads
            float h33 = rbt[2192];   // c=33 (co1, v16)
            float op[3] = {0, 0, 0};
#pragma unroll
            for (int i = 0; i < 4; ++i) {
                float y = acc[i] + cyr[i] + wy32r[i] * h32 + wy33r[i] * h33;
                float z = (y > 0.f) ? y : 0.01f * y;
#pragma unroll
                for (int p = 0; p < 3; ++p) op[p] += w2r[p][i] * z;
            }
#pragma unroll
            for (int p = 0; p < 3; ++p) {
                op[p] += __shfl_xor(op[p], 16);
                op[p] += __shfl_xor(op[p], 32);
            }
            if (l < 16) {
                int tg = seg + ch * 128 + tt * 16 + l;
#pragma unroll
                for (int p = 0; p < 3; ++p)
                    out[((size_t)b * 3 + p) * 2048 + tg] = op[p] + b2r[p];
            }
        }
        __syncthreads();   // drains chunk-1 stage; protects buffer before exit
    }
}

extern "C" void kernel_launch(void* const* d_in, const int* in_sizes, int n_in,
                              void* d_out, int out_size, void* d_ws, size_t ws_size,
                              hipStream_t stream) {
    const float* x     = (const float*)d_in[0];
    const float* wq    = (const float*)d_in[1];
    const float* bq    = (const float*)d_in[2];
    const float* wk    = (const float*)d_in[3];
    const float* bk    = (const float*)d_in[4];
    const float* wv    = (const float*)d_in[5];
    const float* bv    = (const float*)d_in[6];
    const float* w1    = (const float*)d_in[7];
    const float* b1    = (const float*)d_in[8];
    const float* gamma = (const float*)d_in[9];
    const float* beta  = (const float*)d_in[10];
    const float* mean  = (const float*)d_in[11];
    const float* var   = (const float*)d_in[12];
    const float* w2    = (const float*)d_in[13];
    const float* b2    = (const float*)d_in[14];
    float* ws  = (float*)d_ws;
    float* out = (float*)d_out;

    hipMemsetAsync(d_ws, 0, (size_t)NB * GS_STRIDE * sizeof(float), stream);
    k_gram<<<dim3(2048), dim3(256), 0, stream>>>(x, ws);
    k_chain<<<dim3(512), dim3(64), 0, stream>>>(wq, bq, wk, bk, wv, bv,
                                                w1, b1, gamma, beta, mean, var, ws);
    k_out<<<dim3(4096), dim3(256), 0, stream>>>(x, w2, b2, ws, out);
}